// Round 1
// baseline (724.279 us; speedup 1.0000x reference)
//
#include <hip/hip_runtime.h>
#include <cstdint>
#include <cstddef>

#define N_NODES 200000
#define N_FACES 400000
#define N_EDGES (3*N_FACES)
#define NBLK_SCAN 196          // ceil(200000/1024)
#define NB2 3125               // 200000/64, layer2 blocks

typedef __attribute__((ext_vector_type(8))) short short8;
typedef __attribute__((ext_vector_type(4))) float f32x4;

__device__ __forceinline__ float bfl(unsigned u){ return __uint_as_float(u<<16); }
__device__ __forceinline__ float bfh(unsigned u){ return __uint_as_float(u & 0xffff0000u); }
__device__ __forceinline__ unsigned short f2bf(float f){
  unsigned u = __float_as_uint(f);
  u = u + 0x7fffu + ((u>>16)&1u);   // RNE
  return (unsigned short)(u>>16);
}

// ---- CSR build -------------------------------------------------------------
__global__ void k_count(const int* __restrict__ face, int* __restrict__ cnt){
  int e = blockIdx.x*256 + threadIdx.x;
  if (e >= N_EDGES) return;
  int src, dst;
  if (e < 2*N_FACES){ src = face[e]; dst = face[e + N_FACES]; }
  else              { src = face[e - 2*N_FACES]; dst = face[e]; }
  if (src != dst) atomicAdd(&cnt[dst], 1);
}

__global__ void k_scan1(const int* __restrict__ cnt, int* __restrict__ bsums){
  __shared__ int sd[256];
  int t = threadIdx.x, b = blockIdx.x;
  int base = b*1024 + t*4;
  int s = 0;
  #pragma unroll
  for (int k=0;k<4;++k){ int i = base+k; if (i < N_NODES) s += cnt[i]; }
  sd[t] = s; __syncthreads();
  for (int d=1; d<256; d<<=1){
    int v = (t>=d)? sd[t-d] : 0; __syncthreads();
    sd[t] += v; __syncthreads();
  }
  if (t==255) bsums[b] = sd[255];
}

__global__ void k_scan2(const int* __restrict__ bsums, int* __restrict__ bscan){
  if (threadIdx.x==0){
    int r = 0;
    for (int i=0;i<NBLK_SCAN;++i){ bscan[i] = r; r += bsums[i]; }
  }
}

__global__ void k_scan3(const int* __restrict__ cnt, const int* __restrict__ bscan,
                        int* __restrict__ offs, int* __restrict__ fill){
  __shared__ int sd[256];
  int t = threadIdx.x, b = blockIdx.x;
  int base = b*1024 + t*4;
  int c[4]; int s = 0;
  #pragma unroll
  for (int k=0;k<4;++k){ int i = base+k; c[k] = (i < N_NODES)? cnt[i] : 0; s += c[k]; }
  sd[t] = s; __syncthreads();
  int own = s;
  for (int d=1; d<256; d<<=1){
    int v = (t>=d)? sd[t-d] : 0; __syncthreads();
    sd[t] += v; __syncthreads();
  }
  int pre = sd[t] - own + bscan[b];
  #pragma unroll
  for (int k=0;k<4;++k){
    int i = base+k;
    if (i < N_NODES){ offs[i] = pre; fill[i] = pre; pre += c[k]; }
  }
}

__global__ void k_fill(const int* __restrict__ face, int* __restrict__ fill, int* __restrict__ csr){
  int e = blockIdx.x*256 + threadIdx.x;
  if (e >= N_EDGES) return;
  int src, dst;
  if (e < 2*N_FACES){ src = face[e]; dst = face[e + N_FACES]; }
  else              { src = face[e - 2*N_FACES]; dst = face[e]; }
  if (src != dst){ int p = atomicAdd(&fill[dst], 1); csr[p] = src; }
}

// ---- B pre-pack: [W2l;W2r] (512x128) into MFMA fragment order --------------
// Bprep[((s*8+n)*64+l)*8+j] = Bstack[32s+8*(l>>4)+j][16n+(l&15)]
__global__ void k_bprep(const float* __restrict__ W2l, const float* __restrict__ W2r,
                        unsigned short* __restrict__ bp){
  int idx = blockIdx.x*256 + threadIdx.x;   // 65536 total
  int j = idx & 7, l = (idx>>3)&63, n = (idx>>9)&7, s = idx>>12;
  int k = 32*s + 8*(l>>4) + j;
  int c = 16*n + (l&15);
  float v = (k < 256)? W2l[k*128 + c] : W2r[(k-256)*128 + c];
  bp[idx] = f2bf(v);
}

// ---- Layer 1: h1 = relu(agg@W1l + pos@W1r + b1), bf16 out ------------------
__global__ __launch_bounds__(256) void k_h1(
    const float* __restrict__ pos, const int* __restrict__ csr,
    const int* __restrict__ offs, const int* __restrict__ cnt,
    const float* __restrict__ W1l, const float* __restrict__ W1r,
    const float* __restrict__ b1, unsigned short* __restrict__ h1){
  int w = threadIdx.x>>6, lane = threadIdx.x&63;
  int i = blockIdx.x*4 + w;
  int off = offs[i], deg = cnt[i];
  float s0=0.f, s1=0.f, s2=0.f;
  for (int e=lane; e<deg; e+=64){
    int src = csr[off+e];
    const float* p = pos + 3*src;
    s0 += p[0]; s1 += p[1]; s2 += p[2];
  }
  #pragma unroll
  for (int d=1; d<64; d<<=1){
    s0 += __shfl_xor(s0,d); s1 += __shfl_xor(s1,d); s2 += __shfl_xor(s2,d);
  }
  float inv = 1.0f / (float)max(deg,1);
  float a0=s0*inv, a1=s1*inv, a2=s2*inv;
  float p0=pos[3*i], p1=pos[3*i+1], p2=pos[3*i+2];
  unsigned int lo, hi;
  {
    unsigned short o[4];
    #pragma unroll
    for (int j=0;j<4;++j){
      int c = lane*4 + j;
      float v = a0*W1l[c] + a1*W1l[256+c] + a2*W1l[512+c]
              + p0*W1r[c] + p1*W1r[256+c] + p2*W1r[512+c] + b1[c];
      o[j] = f2bf(fmaxf(v, 0.f));
    }
    lo = (unsigned)o[0] | ((unsigned)o[1]<<16);
    hi = (unsigned)o[2] | ((unsigned)o[3]<<16);
  }
  uint2* dst = (uint2*)(h1 + (size_t)i*256 + lane*4);
  *dst = make_uint2(lo, hi);
}

// ---- Layer 2 fused: aggregate(h1) -> MFMA [64x512]@[512x128] -> relu -> rowsum
__global__ __launch_bounds__(256) void k_layer2(
    const unsigned short* __restrict__ h1,
    const int* __restrict__ csr, const int* __restrict__ offs, const int* __restrict__ cnt,
    const unsigned short* __restrict__ bp, const float* __restrict__ b2,
    float* __restrict__ partials){
  __shared__ unsigned short Blds[4*8*64*8];   // 32 KB: 4 ktiles of B frags
  __shared__ float red[128];
  int tid = threadIdx.x;
  int w = tid>>6, lane = tid&63, r = lane&15, g = lane>>4;
  int node = blockIdx.x*64 + w*16 + r;
  if (tid < 128) red[tid] = 0.f;

  int off = offs[node], deg = cnt[node];
  float inv = 1.0f/(float)max(deg,1);

  // aggregation directly into A-fragment layout: lane owns row r, dims 32s+8g..+8
  short8 afragA[8];
  #pragma unroll
  for (int s=0;s<8;++s){
    float a[8] = {0,0,0,0,0,0,0,0};
    int eo = 32*s + 8*g;
    for (int e=0;e<deg;++e){
      int src = csr[off+e];
      uint4 v = *(const uint4*)(h1 + (size_t)src*256 + eo);
      a[0]+=bfl(v.x); a[1]+=bfh(v.x);
      a[2]+=bfl(v.y); a[3]+=bfh(v.y);
      a[4]+=bfl(v.z); a[5]+=bfh(v.z);
      a[6]+=bfl(v.w); a[7]+=bfh(v.w);
    }
    short8 f;
    #pragma unroll
    for (int j=0;j<8;++j) f[j] = (short)f2bf(a[j]*inv);
    afragA[s] = f;
  }

  f32x4 acc[8];
  #pragma unroll
  for (int n=0;n<8;++n) acc[n] = (f32x4){0.f,0.f,0.f,0.f};

  const uint4* bp16 = (const uint4*)bp;
  uint4* bl16 = (uint4*)Blds;
  for (int c4=0; c4<4; ++c4){
    __syncthreads();
    #pragma unroll
    for (int q=0;q<8;++q){
      int t = q*256 + tid;            // 2048 uint4 per chunk
      bl16[t] = bp16[c4*2048 + t];
    }
    __syncthreads();
    #pragma unroll
    for (int s4=0;s4<4;++s4){
      int s = c4*4 + s4;
      short8 af;
      if (s < 8) af = afragA[s];
      else       af = *(const short8*)(h1 + (size_t)node*256 + 32*(s-8) + 8*g);
      #pragma unroll
      for (int n=0;n<8;++n){
        short8 bf = *(const short8*)(Blds + ((size_t)((s4*8+n)*64 + lane))*8);
        acc[n] = __builtin_amdgcn_mfma_f32_16x16x32_bf16(af, bf, acc[n], 0, 0, 0);
      }
    }
  }

  // bias + relu + sum over the 16 rows of this wave's tile
  #pragma unroll
  for (int n=0;n<8;++n){
    float bias = b2[16*n + r];
    float s = 0.f;
    #pragma unroll
    for (int j=0;j<4;++j) s += fmaxf(acc[n][j] + bias, 0.f);
    s += __shfl_xor(s, 16);
    s += __shfl_xor(s, 32);
    if (lane < 16) atomicAdd(&red[16*n + lane], s);
  }
  __syncthreads();
  if (tid < 128) partials[(size_t)blockIdx.x*128 + tid] = red[tid];
}

// ---- reduce partials -> gsum ----------------------------------------------
__global__ void k_red(const float* __restrict__ partials, float* __restrict__ gsum){
  int t = threadIdx.x;  // 128
  float s = 0.f;
  for (int b = blockIdx.x; b < NB2; b += 64) s += partials[(size_t)b*128 + t];
  atomicAdd(&gsum[t], s);
}

// ---- decoder + softmax + argmax -------------------------------------------
__global__ void k_dec(const float* __restrict__ gsum, const float* __restrict__ Wd,
                      const float* __restrict__ bd, float* __restrict__ out, int out_size){
  int lane = threadIdx.x;  // 64
  float l = -1e30f;
  if (lane < 10){
    float s = bd[lane];
    for (int k=0;k<128;++k) s += (gsum[k]*(1.0f/N_NODES)) * Wd[k*10 + lane];
    l = s;
  }
  float m = l;
  #pragma unroll
  for (int d=1; d<16; d<<=1) m = fmaxf(m, __shfl_xor(m, d));
  float e = (lane<10)? expf(l - m) : 0.f;
  float sum = e;
  #pragma unroll
  for (int d=1; d<16; d<<=1) sum += __shfl_xor(sum, d);
  float p = (lane<10)? e/sum : 0.f;
  if (lane < 10) out[lane] = p;
  float v = p; int idx = (lane<10)? lane : 1000;
  #pragma unroll
  for (int d=1; d<16; d<<=1){
    float ov = __shfl_xor(v, d); int oi = __shfl_xor(idx, d);
    if (ov > v || (ov == v && oi < idx)){ v = ov; idx = oi; }
  }
  if (lane == 0 && out_size > 10) out[10] = (float)idx;
}

// ---- launch ----------------------------------------------------------------
extern "C" void kernel_launch(void* const* d_in, const int* in_sizes, int n_in,
                              void* d_out, int out_size, void* d_ws, size_t ws_size,
                              hipStream_t stream){
  const float* pos = (const float*)d_in[0];
  const int*   face= (const int*)  d_in[1];
  const float* W1l = (const float*)d_in[2];
  const float* W1r = (const float*)d_in[3];
  const float* b1  = (const float*)d_in[4];
  const float* W2l = (const float*)d_in[5];
  const float* W2r = (const float*)d_in[6];
  const float* b2  = (const float*)d_in[7];
  const float* Wd  = (const float*)d_in[8];
  const float* bd  = (const float*)d_in[9];

  char* ws = (char*)d_ws;
  size_t o = 0;
  auto alloc = [&](size_t bytes){ size_t rr = o; o += (bytes + 1023) & ~(size_t)1023; return rr; };
  int*   cnt      = (int*)  (ws + alloc((size_t)N_NODES*4));     // off 0, 800768
  float* gsum     = (float*)(ws + alloc(512));                   // right after cnt
  size_t zero_len = o;                                           // memset cnt+gsum together
  int*   offs     = (int*)  (ws + alloc((size_t)(N_NODES+1)*4));
  int*   fill     = (int*)  (ws + alloc((size_t)N_NODES*4));
  int*   bsums    = (int*)  (ws + alloc(1024));
  int*   bscan    = (int*)  (ws + alloc(1024));
  int*   csr      = (int*)  (ws + alloc((size_t)N_EDGES*4));
  unsigned short* bprep = (unsigned short*)(ws + alloc(131072));
  float* partials = (float*)(ws + alloc((size_t)NB2*128*4));
  unsigned short* h1 = (unsigned short*)(ws + alloc((size_t)N_NODES*256*2));

  hipMemsetAsync(ws, 0, zero_len, stream);

  k_bprep<<<256, 256, 0, stream>>>(W2l, W2r, bprep);
  k_count<<<(N_EDGES+255)/256, 256, 0, stream>>>(face, cnt);
  k_scan1<<<NBLK_SCAN, 256, 0, stream>>>(cnt, bsums);
  k_scan2<<<1, 64, 0, stream>>>(bsums, bscan);
  k_scan3<<<NBLK_SCAN, 256, 0, stream>>>(cnt, bscan, offs, fill);
  k_fill<<<(N_EDGES+255)/256, 256, 0, stream>>>(face, fill, csr);
  k_h1<<<N_NODES/4, 256, 0, stream>>>(pos, csr, offs, cnt, W1l, W1r, b1, h1);
  k_layer2<<<NB2, 256, 0, stream>>>(h1, csr, offs, cnt, bprep, b2, partials);
  k_red<<<64, 128, 0, stream>>>(partials, gsum);
  k_dec<<<1, 64, 0, stream>>>(gsum, Wd, bd, (float*)d_out, out_size);
}

// Round 2
// 462.522 us; speedup vs baseline: 1.5659x; 1.5659x over previous
//
#include <hip/hip_runtime.h>
#include <cstdint>
#include <cstddef>

#define N_NODES 200000
#define N_FACES 400000
#define N_EDGES (3*N_FACES)
#define NBLK_SCAN 196          // ceil(200000/1024)
#define NB_MM 3125             // 200000/64 rows per block
#define NB_AGG 2048            // agg2 blocks

typedef __attribute__((ext_vector_type(8))) short short8;
typedef __attribute__((ext_vector_type(4))) float f32x4;

__device__ __forceinline__ float bfl(unsigned u){ return __uint_as_float(u<<16); }
__device__ __forceinline__ float bfh(unsigned u){ return __uint_as_float(u & 0xffff0000u); }
__device__ __forceinline__ unsigned short f2bf(float f){
  unsigned u = __float_as_uint(f);
  u = u + 0x7fffu + ((u>>16)&1u);   // RNE
  return (unsigned short)(u>>16);
}

// ---- CSR build -------------------------------------------------------------
__global__ void k_count(const int* __restrict__ face, int* __restrict__ cnt){
  int e = blockIdx.x*256 + threadIdx.x;
  if (e >= N_EDGES) return;
  int src, dst;
  if (e < 2*N_FACES){ src = face[e]; dst = face[e + N_FACES]; }
  else              { src = face[e - 2*N_FACES]; dst = face[e]; }
  if (src != dst) atomicAdd(&cnt[dst], 1);
}

__global__ void k_scan1(const int* __restrict__ cnt, int* __restrict__ bsums){
  __shared__ int sd[256];
  int t = threadIdx.x, b = blockIdx.x;
  int base = b*1024 + t*4;
  int s = 0;
  #pragma unroll
  for (int k=0;k<4;++k){ int i = base+k; if (i < N_NODES) s += cnt[i]; }
  sd[t] = s; __syncthreads();
  for (int d=1; d<256; d<<=1){
    int v = (t>=d)? sd[t-d] : 0; __syncthreads();
    sd[t] += v; __syncthreads();
  }
  if (t==255) bsums[b] = sd[255];
}

// one wave scans the 196 block sums
__global__ void k_scan2(const int* __restrict__ bsums, int* __restrict__ bscan){
  int l = threadIdx.x;  // 64
  int v[4]; int s = 0;
  #pragma unroll
  for (int k=0;k<4;++k){ int i = l*4+k; v[k] = (i < NBLK_SCAN)? bsums[i] : 0; s += v[k]; }
  int inc = s;
  #pragma unroll
  for (int d=1; d<64; d<<=1){ int t = __shfl_up(inc, d); if (l >= d) inc += t; }
  int pre = inc - s;
  #pragma unroll
  for (int k=0;k<4;++k){ int i = l*4+k; if (i < NBLK_SCAN) bscan[i] = pre; pre += v[k]; }
}

__global__ void k_scan3(const int* __restrict__ cnt, const int* __restrict__ bscan,
                        int* __restrict__ offs, int* __restrict__ fill){
  __shared__ int sd[256];
  int t = threadIdx.x, b = blockIdx.x;
  int base = b*1024 + t*4;
  int c[4]; int s = 0;
  #pragma unroll
  for (int k=0;k<4;++k){ int i = base+k; c[k] = (i < N_NODES)? cnt[i] : 0; s += c[k]; }
  sd[t] = s; __syncthreads();
  int own = s;
  for (int d=1; d<256; d<<=1){
    int v = (t>=d)? sd[t-d] : 0; __syncthreads();
    sd[t] += v; __syncthreads();
  }
  int pre = sd[t] - own + bscan[b];
  #pragma unroll
  for (int k=0;k<4;++k){
    int i = base+k;
    if (i < N_NODES){ offs[i] = pre; fill[i] = pre; pre += c[k]; }
  }
}

__global__ void k_fill(const int* __restrict__ face, int* __restrict__ fill, int* __restrict__ csr){
  int e = blockIdx.x*256 + threadIdx.x;
  if (e >= N_EDGES) return;
  int src, dst;
  if (e < 2*N_FACES){ src = face[e]; dst = face[e + N_FACES]; }
  else              { src = face[e - 2*N_FACES]; dst = face[e]; }
  if (src != dst){ int p = atomicAdd(&fill[dst], 1); csr[p] = src; }
}

// ---- B pre-pack: [W2l|W2r] (256K x 256N) into MFMA fragment order ----------
// bp[((s*16+n)*64+l)*8+j] = Bstack[32s+8*(l>>4)+j][16n+(l&15)]
__global__ void k_bprep(const float* __restrict__ W2l, const float* __restrict__ W2r,
                        unsigned short* __restrict__ bp){
  int idx = blockIdx.x*256 + threadIdx.x;   // 131072 total
  int j = idx & 7, l = (idx>>3)&63, n = (idx>>9)&15, s = idx>>13;
  int k = 32*s + 8*(l>>4) + j;
  int c = 16*n + (l&15);
  float v = (c < 128)? W2l[k*128 + c] : W2r[k*128 + (c-128)];
  bp[idx] = f2bf(v);
}

// ---- agg3: thread per node, mean of neighbor pos --------------------------
__global__ void k_agg3(const float* __restrict__ pos, const int* __restrict__ csr,
                       const int* __restrict__ offs, const int* __restrict__ cnt,
                       float* __restrict__ agg3){
  int i = blockIdx.x*256 + threadIdx.x;
  if (i >= N_NODES) return;
  int off = offs[i], deg = cnt[i];
  float s0=0.f, s1=0.f, s2=0.f;
  int e = 0;
  for (; e+2 <= deg; e += 2){
    int a = csr[off+e], b = csr[off+e+1];
    const float* pa = pos + 3*a; const float* pb = pos + 3*b;
    float a0=pa[0], a1=pa[1], a2=pa[2];
    float b0=pb[0], b1=pb[1], b2v=pb[2];
    s0 += a0 + b0; s1 += a1 + b1; s2 += a2 + b2v;
  }
  if (e < deg){
    const float* pa = pos + 3*csr[off+e];
    s0 += pa[0]; s1 += pa[1]; s2 += pa[2];
  }
  float inv = 1.0f / (float)max(deg,1);
  agg3[3*i] = s0*inv; agg3[3*i+1] = s1*inv; agg3[3*i+2] = s2*inv;
}

// ---- h1 = relu([agg3|pos] @ [W1l;W1r] + b1), bf16, thread per (node, 8 cols)
__global__ __launch_bounds__(256) void k_h1b(
    const float* __restrict__ pos, const float* __restrict__ agg3,
    const float* __restrict__ W1l, const float* __restrict__ W1r,
    const float* __restrict__ b1, unsigned short* __restrict__ h1){
  int idx = blockIdx.x*256 + threadIdx.x;   // 6.4M = 200000*32
  int node = idx >> 5, cg = idx & 31;
  int c0 = cg*8;
  float a0 = agg3[3*node], a1 = agg3[3*node+1], a2 = agg3[3*node+2];
  float p0 = pos[3*node],  p1 = pos[3*node+1], p2 = pos[3*node+2];
  unsigned short o[8];
  #pragma unroll
  for (int j=0;j<8;++j){
    int c = c0 + j;
    float v = a0*W1l[c] + a1*W1l[256+c] + a2*W1l[512+c]
            + p0*W1r[c] + p1*W1r[256+c] + p2*W1r[512+c] + b1[c];
    o[j] = f2bf(fmaxf(v, 0.f));
  }
  uint4 pk;
  pk.x = (unsigned)o[0] | ((unsigned)o[1]<<16);
  pk.y = (unsigned)o[2] | ((unsigned)o[3]<<16);
  pk.z = (unsigned)o[4] | ((unsigned)o[5]<<16);
  pk.w = (unsigned)o[6] | ((unsigned)o[7]<<16);
  *(uint4*)(h1 + (size_t)node*256 + c0) = pk;
}

// ---- dense GEMM (in place): yz[i] = h1[i] @ [W2l|W2r], 64 rows per block ---
__global__ __launch_bounds__(256) void k_mm(
    unsigned short* h1yz,                   // read h1 rows, overwrite with yz
    const unsigned short* __restrict__ bp){
  __shared__ unsigned short Blds[16384];    // 32 KB chunk / epilogue staging
  int tid = threadIdx.x;
  int w = tid>>6, lane = tid&63, r = lane&15, g = lane>>4;
  int base = blockIdx.x*64;

  // A fragments: full 16 rows x 256 K per wave, in registers up front
  const unsigned short* arow = h1yz + (size_t)(base + w*16 + r)*256;
  short8 af[8];
  #pragma unroll
  for (int s=0;s<8;++s) af[s] = *(const short8*)(arow + 32*s + 8*g);

  f32x4 acc[16];
  #pragma unroll
  for (int n=0;n<16;++n) acc[n] = (f32x4){0.f,0.f,0.f,0.f};

  const uint4* bp16 = (const uint4*)bp;
  uint4* bl16 = (uint4*)Blds;
  for (int c4=0; c4<4; ++c4){               // chunks: s = 2c4, 2c4+1
    __syncthreads();
    #pragma unroll
    for (int q=0;q<8;++q) bl16[q*256+tid] = bp16[c4*2048 + q*256 + tid];
    __syncthreads();
    #pragma unroll
    for (int s2=0;s2<2;++s2){
      #pragma unroll
      for (int n=0;n<16;++n){
        short8 bf = *(const short8*)(Blds + ((s2*16+n)*64 + lane)*8);
        acc[n] = __builtin_amdgcn_mfma_f32_16x16x32_bf16(af[2*c4+s2], bf, acc[n], 0, 0, 0);
      }
    }
  }

  // epilogue: stage to LDS [64][256] bf16, then coalesced copy out
  __syncthreads();
  #pragma unroll
  for (int n=0;n<16;++n){
    #pragma unroll
    for (int j=0;j<4;++j){
      Blds[(w*16 + 4*g + j)*256 + 16*n + r] = f2bf(acc[n][j]);
    }
  }
  __syncthreads();
  const uint4* src = (const uint4*)Blds;
  uint4* dst = (uint4*)(h1yz + (size_t)base*256);
  #pragma unroll
  for (int q=0;q<8;++q) dst[q*256+tid] = src[q*256+tid];
}

// ---- gather-aggregate + relu + mean pool: one node per wave ----------------
__global__ __launch_bounds__(256) void k_agg2(
    const unsigned short* __restrict__ yz,
    const int* __restrict__ csr, const int* __restrict__ offs, const int* __restrict__ cnt,
    const float* __restrict__ b2, float* __restrict__ partials){
  __shared__ float red[128];
  int tid = threadIdx.x;
  if (tid < 128) red[tid] = 0.f;
  __syncthreads();
  int lane = tid & 63;
  int wave = blockIdx.x*4 + (tid>>6);
  const int nwaves = NB_AGG*4;
  float bb0 = b2[2*lane], bb1 = b2[2*lane+1];
  float pool0 = 0.f, pool1 = 0.f;

  for (int node = wave; node < N_NODES; node += nwaves){
    int off = offs[node], deg = cnt[node];
    float a0 = 0.f, a1 = 0.f;
    int e = 0;
    for (; e+4 <= deg; e += 4){
      int s0 = csr[off+e], s1 = csr[off+e+1], s2 = csr[off+e+2], s3 = csr[off+e+3];
      unsigned v0 = *(const unsigned*)(yz + ((unsigned)s0<<8) + (lane<<1));
      unsigned v1 = *(const unsigned*)(yz + ((unsigned)s1<<8) + (lane<<1));
      unsigned v2 = *(const unsigned*)(yz + ((unsigned)s2<<8) + (lane<<1));
      unsigned v3 = *(const unsigned*)(yz + ((unsigned)s3<<8) + (lane<<1));
      a0 += bfl(v0) + bfl(v1) + bfl(v2) + bfl(v3);
      a1 += bfh(v0) + bfh(v1) + bfh(v2) + bfh(v3);
    }
    for (; e < deg; ++e){
      int s0 = csr[off+e];
      unsigned v0 = *(const unsigned*)(yz + ((unsigned)s0<<8) + (lane<<1));
      a0 += bfl(v0); a1 += bfh(v0);
    }
    float inv = 1.0f / (float)max(deg,1);
    unsigned vz = *(const unsigned*)(yz + ((unsigned)node<<8) + 128 + (lane<<1));
    float h0 = fmaxf(a0*inv + bfl(vz) + bb0, 0.f);
    float h1v = fmaxf(a1*inv + bfh(vz) + bb1, 0.f);
    pool0 += h0; pool1 += h1v;
  }
  atomicAdd(&red[2*lane],   pool0);
  atomicAdd(&red[2*lane+1], pool1);
  __syncthreads();
  if (tid < 128) partials[(size_t)blockIdx.x*128 + tid] = red[tid];
}

// ---- reduce partials -> gsum ----------------------------------------------
__global__ void k_red(const float* __restrict__ partials, float* __restrict__ gsum){
  int t = threadIdx.x;  // 128
  float s = 0.f;
  for (int b = blockIdx.x; b < NB_AGG; b += 64) s += partials[(size_t)b*128 + t];
  atomicAdd(&gsum[t], s);
}

// ---- decoder + softmax + argmax -------------------------------------------
__global__ void k_dec(const float* __restrict__ gsum, const float* __restrict__ Wd,
                      const float* __restrict__ bd, float* __restrict__ out, int out_size){
  int lane = threadIdx.x;  // 64
  float l = -1e30f;
  if (lane < 10){
    float s = bd[lane];
    for (int k=0;k<128;++k) s += (gsum[k]*(1.0f/N_NODES)) * Wd[k*10 + lane];
    l = s;
  }
  float m = l;
  #pragma unroll
  for (int d=1; d<16; d<<=1) m = fmaxf(m, __shfl_xor(m, d));
  float e = (lane<10)? expf(l - m) : 0.f;
  float sum = e;
  #pragma unroll
  for (int d=1; d<16; d<<=1) sum += __shfl_xor(sum, d);
  float p = (lane<10)? e/sum : 0.f;
  if (lane < 10) out[lane] = p;
  float v = p; int idx = (lane<10)? lane : 1000;
  #pragma unroll
  for (int d=1; d<16; d<<=1){
    float ov = __shfl_xor(v, d); int oi = __shfl_xor(idx, d);
    if (ov > v || (ov == v && oi < idx)){ v = ov; idx = oi; }
  }
  if (lane == 0 && out_size > 10) out[10] = (float)idx;
}

// ---- launch ----------------------------------------------------------------
extern "C" void kernel_launch(void* const* d_in, const int* in_sizes, int n_in,
                              void* d_out, int out_size, void* d_ws, size_t ws_size,
                              hipStream_t stream){
  const float* pos = (const float*)d_in[0];
  const int*   face= (const int*)  d_in[1];
  const float* W1l = (const float*)d_in[2];
  const float* W1r = (const float*)d_in[3];
  const float* b1  = (const float*)d_in[4];
  const float* W2l = (const float*)d_in[5];
  const float* W2r = (const float*)d_in[6];
  const float* b2  = (const float*)d_in[7];
  const float* Wd  = (const float*)d_in[8];
  const float* bd  = (const float*)d_in[9];

  char* ws = (char*)d_ws;
  size_t o = 0;
  auto alloc = [&](size_t bytes){ size_t rr = o; o += (bytes + 1023) & ~(size_t)1023; return rr; };
  int*   cnt      = (int*)  (ws + alloc((size_t)N_NODES*4));
  float* gsum     = (float*)(ws + alloc(512));
  size_t zero_len = o;                                           // memset cnt+gsum together
  int*   offs     = (int*)  (ws + alloc((size_t)N_NODES*4));
  int*   fill     = (int*)  (ws + alloc((size_t)N_NODES*4));
  int*   bsums    = (int*)  (ws + alloc(1024));
  int*   bscan    = (int*)  (ws + alloc(1024));
  int*   csr      = (int*)  (ws + alloc((size_t)N_EDGES*4));
  unsigned short* bprep = (unsigned short*)(ws + alloc(262144));
  float* agg3     = (float*)(ws + alloc((size_t)N_NODES*3*4));
  float* partials = (float*)(ws + alloc((size_t)NB_AGG*128*4));
  unsigned short* h1yz = (unsigned short*)(ws + alloc((size_t)N_NODES*256*2));

  hipMemsetAsync(ws, 0, zero_len, stream);

  k_bprep<<<512, 256, 0, stream>>>(W2l, W2r, bprep);
  k_count<<<(N_EDGES+255)/256, 256, 0, stream>>>(face, cnt);
  k_scan1<<<NBLK_SCAN, 256, 0, stream>>>(cnt, bsums);
  k_scan2<<<1, 64, 0, stream>>>(bsums, bscan);
  k_scan3<<<NBLK_SCAN, 256, 0, stream>>>(cnt, bscan, offs, fill);
  k_fill<<<(N_EDGES+255)/256, 256, 0, stream>>>(face, fill, csr);
  k_agg3<<<(N_NODES+255)/256, 256, 0, stream>>>(pos, csr, offs, cnt, agg3);
  k_h1b<<<25000, 256, 0, stream>>>(pos, agg3, W1l, W1r, b1, h1yz);
  k_mm<<<NB_MM, 256, 0, stream>>>(h1yz, bprep);
  k_agg2<<<NB_AGG, 256, 0, stream>>>(h1yz, csr, offs, cnt, b2, partials);
  k_red<<<64, 128, 0, stream>>>(partials, gsum);
  k_dec<<<1, 64, 0, stream>>>(gsum, Wd, bd, (float*)d_out, out_size);
}

// Round 3
// 430.456 us; speedup vs baseline: 1.6826x; 1.0745x over previous
//
#include <hip/hip_runtime.h>
#include <cstdint>
#include <cstddef>

#define N_NODES 200000
#define N_FACES 400000
#define N_EDGES (3*N_FACES)
#define NBLK_SCAN 196          // ceil(200000/1024)
#define MM_BLOCKS 500          // 12500 row-tiles of 16 rows, 25 per block
#define MM_ITERS 25
#define NB_AGG 2048            // agg2 blocks

typedef __attribute__((ext_vector_type(8))) short short8;
typedef __attribute__((ext_vector_type(4))) float f32x4;

__device__ __forceinline__ float bfl(unsigned u){ return __uint_as_float(u<<16); }
__device__ __forceinline__ float bfh(unsigned u){ return __uint_as_float(u & 0xffff0000u); }
__device__ __forceinline__ unsigned short f2bf(float f){
  unsigned u = __float_as_uint(f);
  u = u + 0x7fffu + ((u>>16)&1u);   // RNE
  return (unsigned short)(u>>16);
}

// ---- CSR build -------------------------------------------------------------
__global__ void k_count(const int* __restrict__ face, int* __restrict__ cnt){
  int e = blockIdx.x*256 + threadIdx.x;
  if (e >= N_EDGES) return;
  int src, dst;
  if (e < 2*N_FACES){ src = face[e]; dst = face[e + N_FACES]; }
  else              { src = face[e - 2*N_FACES]; dst = face[e]; }
  if (src != dst) atomicAdd(&cnt[dst], 1);
}

__global__ void k_scan1(const int* __restrict__ cnt, int* __restrict__ bsums){
  __shared__ int sd[256];
  int t = threadIdx.x, b = blockIdx.x;
  int base = b*1024 + t*4;
  int s = 0;
  #pragma unroll
  for (int k=0;k<4;++k){ int i = base+k; if (i < N_NODES) s += cnt[i]; }
  sd[t] = s; __syncthreads();
  for (int d=1; d<256; d<<=1){
    int v = (t>=d)? sd[t-d] : 0; __syncthreads();
    sd[t] += v; __syncthreads();
  }
  if (t==255) bsums[b] = sd[255];
}

// one wave scans the 196 block sums
__global__ void k_scan2(const int* __restrict__ bsums, int* __restrict__ bscan){
  int l = threadIdx.x;  // 64
  int v[4]; int s = 0;
  #pragma unroll
  for (int k=0;k<4;++k){ int i = l*4+k; v[k] = (i < NBLK_SCAN)? bsums[i] : 0; s += v[k]; }
  int inc = s;
  #pragma unroll
  for (int d=1; d<64; d<<=1){ int t = __shfl_up(inc, d); if (l >= d) inc += t; }
  int pre = inc - s;
  #pragma unroll
  for (int k=0;k<4;++k){ int i = l*4+k; if (i < NBLK_SCAN) bscan[i] = pre; pre += v[k]; }
}

__global__ void k_scan3(const int* __restrict__ cnt, const int* __restrict__ bscan,
                        int* __restrict__ offs, int* __restrict__ fill){
  __shared__ int sd[256];
  int t = threadIdx.x, b = blockIdx.x;
  int base = b*1024 + t*4;
  int c[4]; int s = 0;
  #pragma unroll
  for (int k=0;k<4;++k){ int i = base+k; c[k] = (i < N_NODES)? cnt[i] : 0; s += c[k]; }
  sd[t] = s; __syncthreads();
  int own = s;
  for (int d=1; d<256; d<<=1){
    int v = (t>=d)? sd[t-d] : 0; __syncthreads();
    sd[t] += v; __syncthreads();
  }
  int pre = sd[t] - own + bscan[b];
  #pragma unroll
  for (int k=0;k<4;++k){
    int i = base+k;
    if (i < N_NODES){ offs[i] = pre; fill[i] = pre; pre += c[k]; }
  }
}

__global__ void k_fill(const int* __restrict__ face, int* __restrict__ fill, int* __restrict__ csr){
  int e = blockIdx.x*256 + threadIdx.x;
  if (e >= N_EDGES) return;
  int src, dst;
  if (e < 2*N_FACES){ src = face[e]; dst = face[e + N_FACES]; }
  else              { src = face[e - 2*N_FACES]; dst = face[e]; }
  if (src != dst){ int p = atomicAdd(&fill[dst], 1); csr[p] = src; }
}

// ---- B pre-pack: [W2l|W2r] (256K x 256N) into MFMA fragment order ----------
// bp[((s*16+n)*64+l)*8+j] = Bstack[32s+8*(l>>4)+j][16n+(l&15)]
__global__ void k_bprep(const float* __restrict__ W2l, const float* __restrict__ W2r,
                        unsigned short* __restrict__ bp){
  int idx = blockIdx.x*256 + threadIdx.x;   // 65536 total
  int j = idx & 7, l = (idx>>3)&63, n = (idx>>9)&15, s = idx>>13;
  int k = 32*s + 8*(l>>4) + j;
  int c = 16*n + (l&15);
  float v = (c < 128)? W2l[k*128 + c] : W2r[k*128 + (c-128)];
  bp[idx] = f2bf(v);
}

// ---- agg3: thread per node, mean of neighbor pos --------------------------
__global__ void k_agg3(const float* __restrict__ pos, const int* __restrict__ csr,
                       const int* __restrict__ offs, const int* __restrict__ cnt,
                       float* __restrict__ agg3){
  int i = blockIdx.x*256 + threadIdx.x;
  if (i >= N_NODES) return;
  int off = offs[i], deg = cnt[i];
  float s0=0.f, s1=0.f, s2=0.f;
  int e = 0;
  for (; e+2 <= deg; e += 2){
    int a = csr[off+e], b = csr[off+e+1];
    const float* pa = pos + 3*a; const float* pb = pos + 3*b;
    float a0=pa[0], a1=pa[1], a2=pa[2];
    float b0=pb[0], b1=pb[1], b2v=pb[2];
    s0 += a0 + b0; s1 += a1 + b1; s2 += a2 + b2v;
  }
  if (e < deg){
    const float* pa = pos + 3*csr[off+e];
    s0 += pa[0]; s1 += pa[1]; s2 += pa[2];
  }
  float inv = 1.0f / (float)max(deg,1);
  agg3[3*i] = s0*inv; agg3[3*i+1] = s1*inv; agg3[3*i+2] = s2*inv;
}

// ---- h1 = relu([agg3|pos] @ [W1l;W1r] + b1), bf16, thread per (node, 8 cols)
__global__ __launch_bounds__(256) void k_h1b(
    const float* __restrict__ pos, const float* __restrict__ agg3,
    const float* __restrict__ W1l, const float* __restrict__ W1r,
    const float* __restrict__ b1, unsigned short* __restrict__ h1){
  int idx = blockIdx.x*256 + threadIdx.x;   // 6.4M = 200000*32
  int node = idx >> 5, cg = idx & 31;
  int c0 = cg*8;
  float a0 = agg3[3*node], a1 = agg3[3*node+1], a2 = agg3[3*node+2];
  float p0 = pos[3*node],  p1 = pos[3*node+1], p2 = pos[3*node+2];
  unsigned short o[8];
  #pragma unroll
  for (int j=0;j<8;++j){
    int c = c0 + j;
    float v = a0*W1l[c] + a1*W1l[256+c] + a2*W1l[512+c]
            + p0*W1r[c] + p1*W1r[256+c] + p2*W1r[512+c] + b1[c];
    o[j] = f2bf(fmaxf(v, 0.f));
  }
  uint4 pk;
  pk.x = (unsigned)o[0] | ((unsigned)o[1]<<16);
  pk.y = (unsigned)o[2] | ((unsigned)o[3]<<16);
  pk.z = (unsigned)o[4] | ((unsigned)o[5]<<16);
  pk.w = (unsigned)o[6] | ((unsigned)o[7]<<16);
  *(uint4*)(h1 + (size_t)node*256 + c0) = pk;
}

// ---- dense GEMM (in place): yz[i] = h1[i] @ [W2l|W2r] ----------------------
// Persistent blocks; B column-quarter per wave held in REGISTERS (loaded once);
// 16-row tiles, A double-buffered; one barrier/tile makes the in-place
// overwrite safe (barrier drains vmcnt -> all waves hold A before any store).
__global__ __launch_bounds__(256,2) void k_mm(
    unsigned short* h1yz, const unsigned short* __restrict__ bp){
  __shared__ unsigned Sl[2048];   // 8 KB: per-wave epilogue slice (512 uints each)
  int tid = threadIdx.x;
  int w = tid>>6, lane = tid&63, r = lane&15, g = lane>>4;

  // B frags for cols [64w, 64w+64): n_global = 4w+n4
  short8 B[8][4];
  #pragma unroll
  for (int s=0;s<8;++s)
    #pragma unroll
    for (int n4=0;n4<4;++n4)
      B[s][n4] = *(const short8*)(bp + ((size_t)((s*16 + 4*w + n4)*64 + lane))*8);

  int tile = blockIdx.x;
  short8 afA[8], afB[8];
  {
    const unsigned short* arow = h1yz + (size_t)(tile*16 + r)*256;
    #pragma unroll
    for (int s=0;s<8;++s) afA[s] = *(const short8*)(arow + 32*s + 8*g);
  }

  for (int k=0;k<MM_ITERS;++k){
    int nt = tile + MM_BLOCKS;
    if (k+1 < MM_ITERS){
      const unsigned short* arow2 = h1yz + (size_t)(nt*16 + r)*256;
      #pragma unroll
      for (int s=0;s<8;++s) afB[s] = *(const short8*)(arow2 + 32*s + 8*g);
    }
    f32x4 acc[4];
    #pragma unroll
    for (int n4=0;n4<4;++n4) acc[n4] = (f32x4){0.f,0.f,0.f,0.f};
    #pragma unroll
    for (int s=0;s<8;++s)
      #pragma unroll
      for (int n4=0;n4<4;++n4)
        acc[n4] = __builtin_amdgcn_mfma_f32_16x16x32_bf16(afA[s], B[s][n4], acc[n4], 0, 0, 0);
    __syncthreads();   // drains vmcnt(0): every wave's A(t) (and prefetch) returned
    // pack bf16 pairs via shfl, stage in private slice
    #pragma unroll
    for (int n4=0;n4<4;++n4)
      #pragma unroll
      for (int j=0;j<4;++j){
        unsigned short mu = f2bf(acc[n4][j]);
        unsigned ou = (unsigned)__shfl_xor((int)(unsigned)mu, 1);
        if ((r&1)==0)
          Sl[w*512 + (4*g+j)*32 + 8*n4 + (r>>1)] = (unsigned)mu | (ou<<16);
      }
    // stream own slice out: 16 rows x 128B per wave
    {
      uint4* gdst = (uint4*)(h1yz + (size_t)tile*16*256);
      const uint4* sl4 = (const uint4*)(Sl + w*512);
      #pragma unroll
      for (int q=0;q<2;++q){
        int flat = q*64 + lane;          // 0..127
        int row = flat >> 3, seg = flat & 7;
        gdst[row*32 + w*8 + seg] = sl4[flat];
      }
    }
    #pragma unroll
    for (int s=0;s<8;++s) afA[s] = afB[s];
    tile = nt;
  }
}

// ---- gather-aggregate + relu + mean pool: one node per wave ----------------
__global__ __launch_bounds__(256) void k_agg2(
    const unsigned short* __restrict__ yz,
    const int* __restrict__ csr, const int* __restrict__ offs, const int* __restrict__ cnt,
    const float* __restrict__ b2, float* __restrict__ partials){
  __shared__ float red[128];
  int tid = threadIdx.x;
  if (tid < 128) red[tid] = 0.f;
  __syncthreads();
  int lane = tid & 63;
  int wave = blockIdx.x*4 + (tid>>6);
  const int nwaves = NB_AGG*4;
  float bb0 = b2[2*lane], bb1 = b2[2*lane+1];
  float pool0 = 0.f, pool1 = 0.f;

  for (int node = wave; node < N_NODES; node += nwaves){
    int off = offs[node], deg = cnt[node];
    float a0 = 0.f, a1 = 0.f;
    int e = 0;
    for (; e+4 <= deg; e += 4){
      int s0 = csr[off+e], s1 = csr[off+e+1], s2 = csr[off+e+2], s3 = csr[off+e+3];
      unsigned v0 = *(const unsigned*)(yz + ((unsigned)s0<<8) + (lane<<1));
      unsigned v1 = *(const unsigned*)(yz + ((unsigned)s1<<8) + (lane<<1));
      unsigned v2 = *(const unsigned*)(yz + ((unsigned)s2<<8) + (lane<<1));
      unsigned v3 = *(const unsigned*)(yz + ((unsigned)s3<<8) + (lane<<1));
      a0 += bfl(v0) + bfl(v1) + bfl(v2) + bfl(v3);
      a1 += bfh(v0) + bfh(v1) + bfh(v2) + bfh(v3);
    }
    for (; e < deg; ++e){
      int s0 = csr[off+e];
      unsigned v0 = *(const unsigned*)(yz + ((unsigned)s0<<8) + (lane<<1));
      a0 += bfl(v0); a1 += bfh(v0);
    }
    float inv = 1.0f / (float)max(deg,1);
    unsigned vz = *(const unsigned*)(yz + ((unsigned)node<<8) + 128 + (lane<<1));
    float h0 = fmaxf(a0*inv + bfl(vz) + bb0, 0.f);
    float h1v = fmaxf(a1*inv + bfh(vz) + bb1, 0.f);
    pool0 += h0; pool1 += h1v;
  }
  atomicAdd(&red[2*lane],   pool0);
  atomicAdd(&red[2*lane+1], pool1);
  __syncthreads();
  if (tid < 128) partials[(size_t)blockIdx.x*128 + tid] = red[tid];
}

// ---- reduce partials -> gsum ----------------------------------------------
__global__ void k_red(const float* __restrict__ partials, float* __restrict__ gsum){
  int t = threadIdx.x;  // 128
  float s = 0.f;
  for (int b = blockIdx.x; b < NB_AGG; b += 64) s += partials[(size_t)b*128 + t];
  atomicAdd(&gsum[t], s);
}

// ---- decoder + softmax + argmax -------------------------------------------
__global__ void k_dec(const float* __restrict__ gsum, const float* __restrict__ Wd,
                      const float* __restrict__ bd, float* __restrict__ out, int out_size){
  int lane = threadIdx.x;  // 64
  float l = -1e30f;
  if (lane < 10){
    float s = bd[lane];
    for (int k=0;k<128;++k) s += (gsum[k]*(1.0f/N_NODES)) * Wd[k*10 + lane];
    l = s;
  }
  float m = l;
  #pragma unroll
  for (int d=1; d<16; d<<=1) m = fmaxf(m, __shfl_xor(m, d));
  float e = (lane<10)? expf(l - m) : 0.f;
  float sum = e;
  #pragma unroll
  for (int d=1; d<16; d<<=1) sum += __shfl_xor(sum, d);
  float p = (lane<10)? e/sum : 0.f;
  if (lane < 10) out[lane] = p;
  float v = p; int idx = (lane<10)? lane : 1000;
  #pragma unroll
  for (int d=1; d<16; d<<=1){
    float ov = __shfl_xor(v, d); int oi = __shfl_xor(idx, d);
    if (ov > v || (ov == v && oi < idx)){ v = ov; idx = oi; }
  }
  if (lane == 0 && out_size > 10) out[10] = (float)idx;
}

// ---- launch ----------------------------------------------------------------
extern "C" void kernel_launch(void* const* d_in, const int* in_sizes, int n_in,
                              void* d_out, int out_size, void* d_ws, size_t ws_size,
                              hipStream_t stream){
  const float* pos = (const float*)d_in[0];
  const int*   face= (const int*)  d_in[1];
  const float* W1l = (const float*)d_in[2];
  const float* W1r = (const float*)d_in[3];
  const float* b1  = (const float*)d_in[4];
  const float* W2l = (const float*)d_in[5];
  const float* W2r = (const float*)d_in[6];
  const float* b2  = (const float*)d_in[7];
  const float* Wd  = (const float*)d_in[8];
  const float* bd  = (const float*)d_in[9];

  char* ws = (char*)d_ws;
  size_t o = 0;
  auto alloc = [&](size_t bytes){ size_t rr = o; o += (bytes + 1023) & ~(size_t)1023; return rr; };
  int*   cnt      = (int*)  (ws + alloc((size_t)N_NODES*4));
  float* gsum     = (float*)(ws + alloc(512));
  size_t zero_len = o;                                           // memset cnt+gsum together
  int*   offs     = (int*)  (ws + alloc((size_t)N_NODES*4));
  int*   fill     = (int*)  (ws + alloc((size_t)N_NODES*4));
  int*   bsums    = (int*)  (ws + alloc(1024));
  int*   bscan    = (int*)  (ws + alloc(1024));
  int*   csr      = (int*)  (ws + alloc((size_t)N_EDGES*4));
  unsigned short* bprep = (unsigned short*)(ws + alloc(131072));
  float* agg3     = (float*)(ws + alloc((size_t)N_NODES*3*4));
  float* partials = (float*)(ws + alloc((size_t)NB_AGG*128*4));
  unsigned short* h1yz = (unsigned short*)(ws + alloc((size_t)N_NODES*256*2));

  hipMemsetAsync(ws, 0, zero_len, stream);

  k_bprep<<<256, 256, 0, stream>>>(W2l, W2r, bprep);
  k_count<<<(N_EDGES+255)/256, 256, 0, stream>>>(face, cnt);
  k_scan1<<<NBLK_SCAN, 256, 0, stream>>>(cnt, bsums);
  k_scan2<<<1, 64, 0, stream>>>(bsums, bscan);
  k_scan3<<<NBLK_SCAN, 256, 0, stream>>>(cnt, bscan, offs, fill);
  k_fill<<<(N_EDGES+255)/256, 256, 0, stream>>>(face, fill, csr);
  k_agg3<<<(N_NODES+255)/256, 256, 0, stream>>>(pos, csr, offs, cnt, agg3);
  k_h1b<<<25000, 256, 0, stream>>>(pos, agg3, W1l, W1r, b1, h1yz);
  k_mm<<<MM_BLOCKS, 256, 0, stream>>>(h1yz, bprep);
  k_agg2<<<NB_AGG, 256, 0, stream>>>(h1yz, csr, offs, cnt, b2, partials);
  k_red<<<64, 128, 0, stream>>>(partials, gsum);
  k_dec<<<1, 64, 0, stream>>>(gsum, Wd, bd, (float*)d_out, out_size);
}

// Round 4
// 308.926 us; speedup vs baseline: 2.3445x; 1.3934x over previous
//
#include <hip/hip_runtime.h>
#include <cstdint>
#include <cstddef>

#define N_NODES 200000
#define N_FACES 400000
#define N_EDGES (3*N_FACES)
#define NBUCKETS 196           // ceil(200000/1024), 1024 node-ids per bucket
#define CAP_BUCKET 8192        // mean 6144, sigma~101 -> +20 sigma margin
#define FACES_PER_BLK 2048
#define MM_BLOCKS 500          // 12500 row-tiles of 16 rows, 25 per block
#define MM_ITERS 25
#define NB_AGG 2048            // agg2 blocks

typedef __attribute__((ext_vector_type(8))) short short8;
typedef __attribute__((ext_vector_type(4))) float f32x4;

__device__ __forceinline__ float bfl(unsigned u){ return __uint_as_float(u<<16); }
__device__ __forceinline__ float bfh(unsigned u){ return __uint_as_float(u & 0xffff0000u); }
__device__ __forceinline__ unsigned short f2bf(float f){
  unsigned u = __float_as_uint(f);
  u = u + 0x7fffu + ((u>>16)&1u);   // RNE
  return (unsigned short)(u>>16);
}

// ---- CSR build, pass A: bin (src,dst) pairs by dst>>10 ---------------------
__global__ __launch_bounds__(256) void k_passA(const int* __restrict__ face,
                                               int* __restrict__ bfill,
                                               int2* __restrict__ pairs){
  __shared__ int hist[NBUCKETS], basel[NBUCKETS], rank[NBUCKETS];
  int tid = threadIdx.x;
  if (tid < NBUCKETS) hist[tid] = 0;
  __syncthreads();
  int f0 = blockIdx.x * FACES_PER_BLK + tid;
  int v0[8], v1[8], v2[8];
  #pragma unroll
  for (int k=0;k<8;++k){
    int f = f0 + k*256;
    if (f < N_FACES){
      v0[k] = face[f]; v1[k] = face[f + N_FACES]; v2[k] = face[f + 2*N_FACES];
    } else { v0[k] = 0; v1[k] = 0; v2[k] = 0; }   // degenerate -> all self-loops, skipped
  }
  #pragma unroll
  for (int k=0;k<8;++k){
    if (v0[k] != v1[k]) atomicAdd(&hist[v1[k]>>10], 1);
    if (v1[k] != v2[k]) atomicAdd(&hist[v2[k]>>10], 1);
    if (v0[k] != v2[k]) atomicAdd(&hist[v2[k]>>10], 1);
  }
  __syncthreads();
  if (tid < NBUCKETS){
    basel[tid] = atomicAdd(&bfill[tid], hist[tid]);
    rank[tid] = 0;
  }
  __syncthreads();
  #pragma unroll
  for (int k=0;k<8;++k){
    if (v0[k] != v1[k]){
      int b = v1[k]>>10;
      int p = basel[b] + atomicAdd(&rank[b],1);
      if (p < CAP_BUCKET) pairs[(size_t)b*CAP_BUCKET + p] = make_int2(v0[k], v1[k]);
    }
    if (v1[k] != v2[k]){
      int b = v2[k]>>10;
      int p = basel[b] + atomicAdd(&rank[b],1);
      if (p < CAP_BUCKET) pairs[(size_t)b*CAP_BUCKET + p] = make_int2(v1[k], v2[k]);
    }
    if (v0[k] != v2[k]){
      int b = v2[k]>>10;
      int p = basel[b] + atomicAdd(&rank[b],1);
      if (p < CAP_BUCKET) pairs[(size_t)b*CAP_BUCKET + p] = make_int2(v0[k], v2[k]);
    }
  }
}

// ---- exclusive scan of the 196 bucket fills (one wave) ---------------------
__global__ void k_bscan(const int* __restrict__ bfill, int* __restrict__ bbase){
  int l = threadIdx.x;  // 64
  int v[4]; int s = 0;
  #pragma unroll
  for (int k=0;k<4;++k){ int i = l*4+k; v[k] = (i < NBUCKETS)? min(bfill[i], CAP_BUCKET) : 0; s += v[k]; }
  int inc = s;
  #pragma unroll
  for (int d=1; d<64; d<<=1){ int t = __shfl_up(inc, d); if (l >= d) inc += t; }
  int pre = inc - s;
  #pragma unroll
  for (int k=0;k<4;++k){ int i = l*4+k; if (i < NBUCKETS) bbase[i] = pre; pre += v[k]; }
}

// ---- CSR build, pass B: per-bucket LDS counting sort -----------------------
__global__ __launch_bounds__(512) void k_passB(const int2* __restrict__ pairs,
                                               const int* __restrict__ bfill,
                                               const int* __restrict__ bbase,
                                               int* __restrict__ offs, int* __restrict__ cnt,
                                               int* __restrict__ csr){
  __shared__ int lcnt[1024], lfill[1024], sc[512];
  __shared__ int lcsr[CAP_BUCKET];
  int b = blockIdx.x, tid = threadIdx.x;
  int nb = min(bfill[b], CAP_BUCKET);
  int base = bbase[b];
  const int2* bp = pairs + (size_t)b*CAP_BUCKET;
  lcnt[tid] = 0; lcnt[tid+512] = 0;
  __syncthreads();
  for (int i = tid; i < nb; i += 512){
    int2 e = bp[i];
    atomicAdd(&lcnt[e.y & 1023], 1);
  }
  __syncthreads();
  int c0 = lcnt[2*tid], c1 = lcnt[2*tid+1];
  int s = c0 + c1;
  sc[tid] = s; __syncthreads();
  for (int d=1; d<512; d<<=1){
    int v = (tid>=d)? sc[tid-d] : 0; __syncthreads();
    sc[tid] += v; __syncthreads();
  }
  int excl = sc[tid] - s;
  lfill[2*tid] = excl; lfill[2*tid+1] = excl + c0;
  int g0 = b*1024 + 2*tid, g1 = g0 + 1;
  if (g0 < N_NODES){ offs[g0] = base + excl;      cnt[g0] = c0; }
  if (g1 < N_NODES){ offs[g1] = base + excl + c0; cnt[g1] = c1; }
  __syncthreads();
  for (int i = tid; i < nb; i += 512){
    int2 e = bp[i];
    int p = atomicAdd(&lfill[e.y & 1023], 1);
    lcsr[p] = e.x;
  }
  __syncthreads();
  for (int i = tid; i < nb; i += 512){
    csr[base + i] = lcsr[i];
  }
}

// ---- B pre-pack: [W2l|W2r] (256K x 256N) into MFMA fragment order ----------
// bp[((s*16+n)*64+l)*8+j] = Bstack[32s+8*(l>>4)+j][16n+(l&15)]
__global__ void k_bprep(const float* __restrict__ W2l, const float* __restrict__ W2r,
                        unsigned short* __restrict__ bp){
  int idx = blockIdx.x*256 + threadIdx.x;   // 65536 total
  int j = idx & 7, l = (idx>>3)&63, n = (idx>>9)&15, s = idx>>13;
  int k = 32*s + 8*(l>>4) + j;
  int c = 16*n + (l&15);
  float v = (c < 128)? W2l[k*128 + c] : W2r[k*128 + (c-128)];
  bp[idx] = f2bf(v);
}

// ---- agg3: thread per node, mean of neighbor pos --------------------------
__global__ void k_agg3(const float* __restrict__ pos, const int* __restrict__ csr,
                       const int* __restrict__ offs, const int* __restrict__ cnt,
                       float* __restrict__ agg3){
  int i = blockIdx.x*256 + threadIdx.x;
  if (i >= N_NODES) return;
  int off = offs[i], deg = cnt[i];
  float s0=0.f, s1=0.f, s2=0.f;
  int e = 0;
  for (; e+2 <= deg; e += 2){
    int a = csr[off+e], b = csr[off+e+1];
    const float* pa = pos + 3*a; const float* pb = pos + 3*b;
    float a0=pa[0], a1=pa[1], a2=pa[2];
    float b0=pb[0], b1=pb[1], b2v=pb[2];
    s0 += a0 + b0; s1 += a1 + b1; s2 += a2 + b2v;
  }
  if (e < deg){
    const float* pa = pos + 3*csr[off+e];
    s0 += pa[0]; s1 += pa[1]; s2 += pa[2];
  }
  float inv = 1.0f / (float)max(deg,1);
  agg3[3*i] = s0*inv; agg3[3*i+1] = s1*inv; agg3[3*i+2] = s2*inv;
}

// ---- h1 = relu([agg3|pos] @ [W1l;W1r] + b1), bf16, thread per (node, 8 cols)
__global__ __launch_bounds__(256) void k_h1b(
    const float* __restrict__ pos, const float* __restrict__ agg3,
    const float* __restrict__ W1l, const float* __restrict__ W1r,
    const float* __restrict__ b1, unsigned short* __restrict__ h1){
  int idx = blockIdx.x*256 + threadIdx.x;   // 6.4M = 200000*32
  int node = idx >> 5, cg = idx & 31;
  int c0 = cg*8;
  float a0 = agg3[3*node], a1 = agg3[3*node+1], a2 = agg3[3*node+2];
  float p0 = pos[3*node],  p1 = pos[3*node+1], p2 = pos[3*node+2];
  unsigned short o[8];
  #pragma unroll
  for (int j=0;j<8;++j){
    int c = c0 + j;
    float v = a0*W1l[c] + a1*W1l[256+c] + a2*W1l[512+c]
            + p0*W1r[c] + p1*W1r[256+c] + p2*W1r[512+c] + b1[c];
    o[j] = f2bf(fmaxf(v, 0.f));
  }
  uint4 pk;
  pk.x = (unsigned)o[0] | ((unsigned)o[1]<<16);
  pk.y = (unsigned)o[2] | ((unsigned)o[3]<<16);
  pk.z = (unsigned)o[4] | ((unsigned)o[5]<<16);
  pk.w = (unsigned)o[6] | ((unsigned)o[7]<<16);
  *(uint4*)(h1 + (size_t)node*256 + c0) = pk;
}

// ---- dense GEMM (in place): yz[i] = h1[i] @ [W2l|W2r] ----------------------
// Persistent blocks; B column-quarter per wave held in REGISTERS (loaded once);
// 16-row tiles, A double-buffered; one barrier/tile makes the in-place
// overwrite safe (barrier drains vmcnt -> all waves hold A before any store).
__global__ __launch_bounds__(256,2) void k_mm(
    unsigned short* h1yz, const unsigned short* __restrict__ bp){
  __shared__ unsigned Sl[2048];   // 8 KB: per-wave epilogue slice (512 uints each)
  int tid = threadIdx.x;
  int w = tid>>6, lane = tid&63, r = lane&15, g = lane>>4;

  short8 B[8][4];
  #pragma unroll
  for (int s=0;s<8;++s)
    #pragma unroll
    for (int n4=0;n4<4;++n4)
      B[s][n4] = *(const short8*)(bp + ((size_t)((s*16 + 4*w + n4)*64 + lane))*8);

  int tile = blockIdx.x;
  short8 afA[8], afB[8];
  {
    const unsigned short* arow = h1yz + (size_t)(tile*16 + r)*256;
    #pragma unroll
    for (int s=0;s<8;++s) afA[s] = *(const short8*)(arow + 32*s + 8*g);
  }

  for (int k=0;k<MM_ITERS;++k){
    int nt = tile + MM_BLOCKS;
    if (k+1 < MM_ITERS){
      const unsigned short* arow2 = h1yz + (size_t)(nt*16 + r)*256;
      #pragma unroll
      for (int s=0;s<8;++s) afB[s] = *(const short8*)(arow2 + 32*s + 8*g);
    }
    f32x4 acc[4];
    #pragma unroll
    for (int n4=0;n4<4;++n4) acc[n4] = (f32x4){0.f,0.f,0.f,0.f};
    #pragma unroll
    for (int s=0;s<8;++s)
      #pragma unroll
      for (int n4=0;n4<4;++n4)
        acc[n4] = __builtin_amdgcn_mfma_f32_16x16x32_bf16(afA[s], B[s][n4], acc[n4], 0, 0, 0);
    __syncthreads();   // drains vmcnt(0): every wave's A(t) (and prefetch) returned
    #pragma unroll
    for (int n4=0;n4<4;++n4)
      #pragma unroll
      for (int j=0;j<4;++j){
        unsigned short mu = f2bf(acc[n4][j]);
        unsigned ou = (unsigned)__shfl_xor((int)(unsigned)mu, 1);
        if ((r&1)==0)
          Sl[w*512 + (4*g+j)*32 + 8*n4 + (r>>1)] = (unsigned)mu | (ou<<16);
      }
    {
      uint4* gdst = (uint4*)(h1yz + (size_t)tile*16*256);
      const uint4* sl4 = (const uint4*)(Sl + w*512);
      #pragma unroll
      for (int q=0;q<2;++q){
        int flat = q*64 + lane;          // 0..127
        int row = flat >> 3, seg = flat & 7;
        gdst[row*32 + w*8 + seg] = sl4[flat];
      }
    }
    #pragma unroll
    for (int s=0;s<8;++s) afA[s] = afB[s];
    tile = nt;
  }
}

// ---- gather-aggregate + relu + mean pool: one node per wave ----------------
__global__ __launch_bounds__(256) void k_agg2(
    const unsigned short* __restrict__ yz,
    const int* __restrict__ csr, const int* __restrict__ offs, const int* __restrict__ cnt,
    const float* __restrict__ b2, float* __restrict__ partials){
  __shared__ float red[128];
  int tid = threadIdx.x;
  if (tid < 128) red[tid] = 0.f;
  __syncthreads();
  int lane = tid & 63;
  int wave = blockIdx.x*4 + (tid>>6);
  const int nwaves = NB_AGG*4;
  float bb0 = b2[2*lane], bb1 = b2[2*lane+1];
  float pool0 = 0.f, pool1 = 0.f;

  for (int node = wave; node < N_NODES; node += nwaves){
    int off = offs[node], deg = cnt[node];
    float a0 = 0.f, a1 = 0.f;
    int e = 0;
    for (; e+4 <= deg; e += 4){
      int s0 = csr[off+e], s1 = csr[off+e+1], s2 = csr[off+e+2], s3 = csr[off+e+3];
      unsigned v0 = *(const unsigned*)(yz + ((unsigned)s0<<8) + (lane<<1));
      unsigned v1 = *(const unsigned*)(yz + ((unsigned)s1<<8) + (lane<<1));
      unsigned v2 = *(const unsigned*)(yz + ((unsigned)s2<<8) + (lane<<1));
      unsigned v3 = *(const unsigned*)(yz + ((unsigned)s3<<8) + (lane<<1));
      a0 += bfl(v0) + bfl(v1) + bfl(v2) + bfl(v3);
      a1 += bfh(v0) + bfh(v1) + bfh(v2) + bfh(v3);
    }
    for (; e < deg; ++e){
      int s0 = csr[off+e];
      unsigned v0 = *(const unsigned*)(yz + ((unsigned)s0<<8) + (lane<<1));
      a0 += bfl(v0); a1 += bfh(v0);
    }
    float inv = 1.0f / (float)max(deg,1);
    unsigned vz = *(const unsigned*)(yz + ((unsigned)node<<8) + 128 + (lane<<1));
    float h0 = fmaxf(a0*inv + bfl(vz) + bb0, 0.f);
    float h1v = fmaxf(a1*inv + bfh(vz) + bb1, 0.f);
    pool0 += h0; pool1 += h1v;
  }
  atomicAdd(&red[2*lane],   pool0);
  atomicAdd(&red[2*lane+1], pool1);
  __syncthreads();
  if (tid < 128) partials[(size_t)blockIdx.x*128 + tid] = red[tid];
}

// ---- reduce partials -> gsum ----------------------------------------------
__global__ void k_red(const float* __restrict__ partials, float* __restrict__ gsum){
  int t = threadIdx.x;  // 128
  float s = 0.f;
  for (int b = blockIdx.x; b < NB_AGG; b += 64) s += partials[(size_t)b*128 + t];
  atomicAdd(&gsum[t], s);
}

// ---- decoder + softmax + argmax -------------------------------------------
__global__ void k_dec(const float* __restrict__ gsum, const float* __restrict__ Wd,
                      const float* __restrict__ bd, float* __restrict__ out, int out_size){
  int lane = threadIdx.x;  // 64
  float l = -1e30f;
  if (lane < 10){
    float s = bd[lane];
    for (int k=0;k<128;++k) s += (gsum[k]*(1.0f/N_NODES)) * Wd[k*10 + lane];
    l = s;
  }
  float m = l;
  #pragma unroll
  for (int d=1; d<16; d<<=1) m = fmaxf(m, __shfl_xor(m, d));
  float e = (lane<10)? expf(l - m) : 0.f;
  float sum = e;
  #pragma unroll
  for (int d=1; d<16; d<<=1) sum += __shfl_xor(sum, d);
  float p = (lane<10)? e/sum : 0.f;
  if (lane < 10) out[lane] = p;
  float v = p; int idx = (lane<10)? lane : 1000;
  #pragma unroll
  for (int d=1; d<16; d<<=1){
    float ov = __shfl_xor(v, d); int oi = __shfl_xor(idx, d);
    if (ov > v || (ov == v && oi < idx)){ v = ov; idx = oi; }
  }
  if (lane == 0 && out_size > 10) out[10] = (float)idx;
}

// ---- launch ----------------------------------------------------------------
extern "C" void kernel_launch(void* const* d_in, const int* in_sizes, int n_in,
                              void* d_out, int out_size, void* d_ws, size_t ws_size,
                              hipStream_t stream){
  const float* pos = (const float*)d_in[0];
  const int*   face= (const int*)  d_in[1];
  const float* W1l = (const float*)d_in[2];
  const float* W1r = (const float*)d_in[3];
  const float* b1  = (const float*)d_in[4];
  const float* W2l = (const float*)d_in[5];
  const float* W2r = (const float*)d_in[6];
  const float* b2  = (const float*)d_in[7];
  const float* Wd  = (const float*)d_in[8];
  const float* bd  = (const float*)d_in[9];

  char* ws = (char*)d_ws;
  size_t o = 0;
  auto alloc = [&](size_t bytes){ size_t rr = o; o += (bytes + 1023) & ~(size_t)1023; return rr; };
  int*   bfill    = (int*)  (ws + alloc(NBUCKETS*4));            // zeroed
  float* gsum     = (float*)(ws + alloc(512));                   // zeroed
  size_t zero_len = o;
  int*   bbase    = (int*)  (ws + alloc(NBUCKETS*4));
  int*   offs     = (int*)  (ws + alloc((size_t)N_NODES*4));
  int*   cnt      = (int*)  (ws + alloc((size_t)N_NODES*4));
  int*   csr      = (int*)  (ws + alloc((size_t)N_EDGES*4));
  unsigned short* bprep = (unsigned short*)(ws + alloc(131072));
  float* agg3     = (float*)(ws + alloc((size_t)N_NODES*3*4));
  float* partials = (float*)(ws + alloc((size_t)NB_AGG*128*4));
  unsigned short* h1yz = (unsigned short*)(ws + alloc((size_t)N_NODES*256*2));
  int2*  pairs    = (int2*)h1yz;   // 12.8 MB, dead before k_h1b writes h1yz

  hipMemsetAsync(ws, 0, zero_len, stream);

  k_bprep<<<256, 256, 0, stream>>>(W2l, W2r, bprep);
  k_passA<<<NBUCKETS, 256, 0, stream>>>(face, bfill, pairs);
  k_bscan<<<1, 64, 0, stream>>>(bfill, bbase);
  k_passB<<<NBUCKETS, 512, 0, stream>>>(pairs, bfill, bbase, offs, cnt, csr);
  k_agg3<<<(N_NODES+255)/256, 256, 0, stream>>>(pos, csr, offs, cnt, agg3);
  k_h1b<<<25000, 256, 0, stream>>>(pos, agg3, W1l, W1r, b1, h1yz);
  k_mm<<<MM_BLOCKS, 256, 0, stream>>>(h1yz, bprep);
  k_agg2<<<NB_AGG, 256, 0, stream>>>(h1yz, csr, offs, cnt, b2, partials);
  k_red<<<64, 128, 0, stream>>>(partials, gsum);
  k_dec<<<1, 64, 0, stream>>>(gsum, Wd, bd, (float*)d_out, out_size);
}